// Round 12
// baseline (357.514 us; speedup 1.0000x reference)
//
#include <hip/hip_runtime.h>
#include <hip/hip_fp16.h>

#define TT 256
#define DD 128
#define NEG -30000.0f

typedef __attribute__((ext_vector_type(4))) float f32x4;
typedef __attribute__((ext_vector_type(8))) _Float16 f16x8;
typedef unsigned int u32;
typedef __attribute__((ext_vector_type(4))) u32 u32x4;
typedef unsigned short u16;

__device__ __forceinline__ u16 tof16(float v) {
  return __builtin_bit_cast(u16, (_Float16)v);
}
__device__ __forceinline__ u32 pkf16(float lo, float hi) {
  return (u32)tof16(lo) | ((u32)tof16(hi) << 16);
}
__device__ __forceinline__ f32x4 mfma16(f16x8 a, f16x8 b, f32x4 c) {
  return __builtin_amdgcn_mfma_f32_16x16x32_f16(a, b, c, 0, 0, 0);
}

// D-layout -> operand-frag repack (verified rounds 2-11). src[2P] D-tiles
// (rows t*16+g*4+j, col l15) -> dst[P] frags: lane(l15,g) holds packed f16 of
// M[col=l15][row=p*32+g*8+0..7].
template<int P>
__device__ __forceinline__ void convN(const f32x4* src, u32x4* dst, int l15, int g) {
  #pragma unroll
  for (int p = 0; p < P; ++p) {
    u32 p00 = pkf16(src[2*p][0], src[2*p][1]);
    u32 p01 = pkf16(src[2*p][2], src[2*p][3]);
    u32 p10 = pkf16(src[2*p+1][0], src[2*p+1][1]);
    u32 p11 = pkf16(src[2*p+1][2], src[2*p+1][3]);
    u32x4 w;
    #pragma unroll
    for (int wd = 0; wd < 4; ++wd) {
      int srcl = l15 + 16*((2*g + (wd >> 1)) & 3);
      u32 lo = (u32)__shfl((int)((wd & 1) ? p01 : p00), srcl, 64);
      u32 hi = (u32)__shfl((int)((wd & 1) ? p11 : p10), srcl, 64);
      w[wd] = (g >> 1) ? hi : lo;
    }
    dst[p] = w;
  }
}

// ---------------- precompute: MT[d'][d] = sum_e Wq[e][d]Wk[e][d']; WvB=f16(Wv);
// m0[d] = sum_e bq[e]Wk[e][d]   (verified round 2)
__global__ void precompute_k(const float* __restrict__ Wk, const float* __restrict__ Wq,
                             const float* __restrict__ bq, const float* __restrict__ Wv,
                             u16* __restrict__ MT, u16* __restrict__ WvB, float* __restrict__ m0) {
  int dp = blockIdx.x;
  int d  = threadIdx.x;
  float acc = 0.f;
  for (int e = 0; e < DD; ++e) acc = fmaf(Wq[e*DD + d], Wk[e*DD + dp], acc);
  MT[dp*DD + d] = tof16(acc);
  WvB[dp*DD + d] = tof16(Wv[dp*DD + d]);
  if (dp == 0) {
    float a0 = 0.f;
    for (int e = 0; e < DD; ++e) a0 = fmaf(bq[e], Wk[e*DD + d], a0);
    m0[d] = a0;
  }
}

// Phase A (verified): A'-strip for q-tile qt -> B-frags bAw
__device__ __forceinline__ void phaseA(int qt, const char* __restrict__ xhb,
                                       const u16* __restrict__ MTg,
                                       const float* __restrict__ m0g,
                                       u32x4 (&bAw)[4], const int (&xoff)[4],
                                       int l15, int g) {
  f16x8 bXq[4];
  #pragma unroll
  for (int kc = 0; kc < 4; ++kc)
    bXq[kc] = *(const f16x8*)(xhb + qt*4096 + xoff[kc]);
  f32x4 Aacc[8];
  #pragma unroll
  for (int dt = 0; dt < 8; ++dt) {
    f32x4 acc = {0.f, 0.f, 0.f, 0.f};
    #pragma unroll
    for (int kc = 0; kc < 4; ++kc) {
      f16x8 aM = *(const f16x8*)(MTg + (dt*16 + l15)*DD + kc*32 + g*8);
      acc = mfma16(aM, bXq[kc], acc);
    }
    f32x4 m0v = *(const f32x4*)(m0g + dt*16 + g*4);
    #pragma unroll
    for (int j = 0; j < 4; ++j) acc[j] += m0v[j];
    Aacc[dt] = acc;
  }
  convN<4>(Aacc, bAw, l15, g);
}

// One online-softmax chunk for q-tile qt (verified r7-r11): S pair -> running
// max (defer THR=8) -> exp -> pf B-frag. Updates m, sum; rescales oacc.
__device__ __forceinline__ f16x8 chunk_sm(int qt, int c, const f16x8 (&aX0)[4],
                                          const f16x8 (&aX1)[4], const u32x4 (&bAw)[4],
                                          f32x4 (&oacc)[8], float& m, float& sum,
                                          int l15, int g) {
  const int kt0 = 2*c, kt1 = 2*c + 1;
  f32x4 s0 = {0.f, 0.f, 0.f, 0.f};
  f32x4 s1 = {NEG, NEG, NEG, NEG};
  #pragma unroll
  for (int kc = 0; kc < 4; ++kc)
    s0 = mfma16(aX0[kc], __builtin_bit_cast(f16x8, bAw[kc]), s0);
  if (kt0 == qt) {
    #pragma unroll
    for (int j = 0; j < 4; ++j)
      if (g*4 + j > l15) s0[j] = NEG;
  }
  if (kt1 <= qt) {
    f32x4 acc = {0.f, 0.f, 0.f, 0.f};
    #pragma unroll
    for (int kc = 0; kc < 4; ++kc)
      acc = mfma16(aX1[kc], __builtin_bit_cast(f16x8, bAw[kc]), acc);
    if (kt1 == qt) {
      #pragma unroll
      for (int j = 0; j < 4; ++j)
        if (g*4 + j > l15) acc[j] = NEG;
    }
    s1 = acc;
  }
  float pmax = NEG;
  #pragma unroll
  for (int j = 0; j < 4; ++j) pmax = fmaxf(pmax, fmaxf(s0[j], s1[j]));
  pmax = fmaxf(pmax, __shfl_xor(pmax, 16));
  pmax = fmaxf(pmax, __shfl_xor(pmax, 32));
  if (!__all(pmax <= m + 8.f)) {
    float mn = fmaxf(m, pmax);
    float f  = __expf(m - mn);          // 0 on first chunk (m=NEG)
    sum *= f;
    #pragma unroll
    for (int et = 0; et < 8; ++et) {
      #pragma unroll
      for (int j = 0; j < 4; ++j) oacc[et][j] *= f;
    }
    m = mn;
  }
  #pragma unroll
  for (int j = 0; j < 4; ++j) {
    float p0 = __expf(s0[j] - m); s0[j] = p0; sum += p0;
    float p1 = __expf(s1[j] - m); s1[j] = p1; sum += p1;    // 0 if kt1 invalid
  }
  u32 p00 = pkf16(s0[0], s0[1]);
  u32 p01 = pkf16(s0[2], s0[3]);
  u32 p10 = pkf16(s1[0], s1[1]);
  u32 p11 = pkf16(s1[2], s1[3]);
  u32x4 pw;
  #pragma unroll
  for (int wd = 0; wd < 4; ++wd) {
    int srcl = l15 + 16*((2*g + (wd >> 1)) & 3);
    u32 lo = (u32)__shfl((int)((wd & 1) ? p01 : p00), srcl, 64);
    u32 hi = (u32)__shfl((int)((wd & 1) ? p11 : p10), srcl, 64);
    pw[wd] = (g >> 1) ? hi : lo;
  }
  return __builtin_bit_cast(f16x8, pw);
}

// ---------------- fused head: 1 block = 1 batch, 8 waves (512 thr), 128 KB LDS.
// Wave w handles the balanced pair {15-w, w} (9 chunks total) with a MERGED
// chunk loop: shared aX/aV loads, two independent softmax/MFMA chains (2x ILP
// at our LDS-capped 2 waves/SIMD). amdgpu_waves_per_eu(2,2) pins the allocator
// to the 256-VGPR budget that occupancy already permits (r8's spill was the
// allocator targeting 4 waves/EU = 128 regs).
__global__ __launch_bounds__(512)
__attribute__((amdgpu_waves_per_eu(2, 2)))
void head_fused(const float* __restrict__ x, const u16* __restrict__ MTg,
                const u16* __restrict__ WvB, const float* __restrict__ m0g,
                const float* __restrict__ bvg, float* __restrict__ out) {
  extern __shared__ char lds[];
  char* xhb = lds;            // xh frags (64 KB, swizzled: l15s = l15 ^ (kc*4+g))
  char* vtb = lds + 65536;    // vt frags (64 KB, linear)

  const int tid  = threadIdx.x;
  const int w    = tid >> 6;
  const int lane = tid & 63;
  const int l15  = lane & 15;
  const int g    = lane >> 4;
  const int b    = blockIdx.x;
  const float* xb = x + (size_t)b * (TT*DD);

  int xoff[4];
  #pragma unroll
  for (int kc = 0; kc < 4; ++kc)
    xoff[kc] = kc*1024 + g*256 + (l15 ^ (kc*4 + g))*16;
  const int voff = g*256 + l15*16;

  // ---- Stage: x f32 -> f16 frags in LDS (verified r9/r11)
  #pragma unroll
  for (int i = 0; i < 8; ++i) {
    int slot = tid + i*512;
    int row = slot >> 4, cg = slot & 15;
    const float* p = xb + row*DD + cg*8;
    f32x4 v0 = *(const f32x4*)p, v1 = *(const f32x4*)(p + 4);
    u32x4 pk;
    pk[0] = pkf16(v0[0], v0[1]); pk[1] = pkf16(v0[2], v0[3]);
    pk[2] = pkf16(v1[0], v1[1]); pk[3] = pkf16(v1[2], v1[3]);
    *(u32x4*)(xhb + (row >> 4)*4096 + (cg >> 2)*1024 + (cg & 3)*256
                  + ((row & 15) ^ cg)*16) = pk;
  }
  __syncthreads();

  // ---- VT: wave w builds vt chunk c=w, all 8 et (verified r8-r11 math)
  {
    const int c = w;
    f16x8 bX[2][4];
    #pragma unroll
    for (int t = 0; t < 2; ++t)
      #pragma unroll
      for (int kc = 0; kc < 4; ++kc)
        bX[t][kc] = *(const f16x8*)(xhb + (2*c + t)*4096 + xoff[kc]);
    #pragma unroll
    for (int et = 0; et < 8; ++et) {
      f16x8 bWv[4];
      #pragma unroll
      for (int kc = 0; kc < 4; ++kc)
        bWv[kc] = *(const f16x8*)(WvB + (et*16 + l15)*DD + kc*32 + g*8);
      f32x4 vacc[2];
      #pragma unroll
      for (int t = 0; t < 2; ++t) {
        f32x4 acc = {0.f, 0.f, 0.f, 0.f};
        #pragma unroll
        for (int kc = 0; kc < 4; ++kc) acc = mfma16(bX[t][kc], bWv[kc], acc);
        vacc[t] = acc;
      }
      u32x4 dv[1];
      convN<1>(vacc, dv, l15, g);
      *(u32x4*)(vtb + et*8192 + c*1024 + voff) = dv[0];
    }
  }
  __syncthreads();

  // ---- Phase A for both tiles (transient Aacc dies inside each call)
  const int qa = w, qb = 15 - w;
  u32x4 bAwA[4], bAwB[4];
  phaseA(qa, xhb, MTg, m0g, bAwA, xoff, l15, g);
  phaseA(qb, xhb, MTg, m0g, bAwB, xoff, l15, g);

  // ---- Merged online chunk loop: two independent chains share aX/aV loads
  const int nchA = (qa + 2) >> 1;
  const int nchB = (qb + 2) >> 1;     // nchB >= nchA for w = 0..7
  f32x4 oA[8], oB[8];
  #pragma unroll
  for (int et = 0; et < 8; ++et) {
    f32x4 z = {0.f, 0.f, 0.f, 0.f};
    oA[et] = z; oB[et] = z;
  }
  float mA = NEG, sA = 0.f, mB = NEG, sB = 0.f;

  #pragma unroll 1
  for (int c = 0; c < nchB; ++c) {
    f16x8 aX0[4], aX1[4];
    #pragma unroll
    for (int kc = 0; kc < 4; ++kc) {
      aX0[kc] = *(const f16x8*)(xhb + (2*c)*4096     + xoff[kc]);
      aX1[kc] = *(const f16x8*)(xhb + (2*c + 1)*4096 + xoff[kc]);
    }
    const bool da = c < nchA;
    f16x8 pbB = chunk_sm(qb, c, aX0, aX1, bAwB, oB, mB, sB, l15, g);
    f16x8 pbA;
    if (da) pbA = chunk_sm(qa, c, aX0, aX1, bAwA, oA, mA, sA, l15, g);
    #pragma unroll
    for (int et = 0; et < 8; ++et) {
      f16x8 aV = *(const f16x8*)(vtb + et*8192 + c*1024 + voff);
      oB[et] = mfma16(aV, pbB, oB[et]);
      if (da) oA[et] = mfma16(aV, pbA, oA[et]);
    }
  }

  // ---- Epilogue: normalize + bv; store both tiles (verified layout)
  sA += __shfl_xor(sA, 16); sA += __shfl_xor(sA, 32);
  sB += __shfl_xor(sB, 16); sB += __shfl_xor(sB, 32);
  const float invA = 1.f / sA, invB = 1.f / sB;
  float* outb = out + (size_t)b * (TT*DD);
  #pragma unroll
  for (int et = 0; et < 8; ++et) {
    f32x4 bvv = *(const f32x4*)(bvg + et*16 + g*4);
    f32x4 oa, ob;
    #pragma unroll
    for (int j = 0; j < 4; ++j) {
      oa[j] = oA[et][j]*invA + bvv[j];
      ob[j] = oB[et][j]*invB + bvv[j];
    }
    *(f32x4*)(outb + (qa*16 + l15)*DD + et*16 + g*4) = oa;
    *(f32x4*)(outb + (qb*16 + l15)*DD + et*16 + g*4) = ob;
  }
}

// ================= launcher =================
extern "C" void kernel_launch(void* const* d_in, const int* in_sizes, int n_in,
                              void* d_out, int out_size, void* d_ws, size_t ws_size,
                              hipStream_t stream) {
  (void)in_sizes; (void)n_in; (void)out_size; (void)ws_size;
  const float* x  = (const float*)d_in[0];
  const float* Wk = (const float*)d_in[1];
  // d_in[2] = bk: only per-q-row constants in scores -> dropped by softmax
  const float* Wq = (const float*)d_in[3];
  const float* bq = (const float*)d_in[4];
  const float* Wv = (const float*)d_in[5];
  const float* bv = (const float*)d_in[6];

  char* ws = (char*)d_ws;
  u16*   MT  = (u16*)ws;               // 32 KB
  u16*   WvB = (u16*)(ws + 32768);     // 32 KB
  float* m0  = (float*)(ws + 65536);   // 512 B

  (void)hipFuncSetAttribute((const void*)head_fused,
                            hipFuncAttributeMaxDynamicSharedMemorySize, 131072);

  precompute_k<<<128, 128, 0, stream>>>(Wk, Wq, bq, Wv, MT, WvB, m0);
  head_fused<<<512, 512, 131072, stream>>>(x, MT, WvB, m0, bv, (float*)d_out);
}

// Round 15
// 127.143 us; speedup vs baseline: 2.8119x; 2.8119x over previous
//
#include <hip/hip_runtime.h>
#include <hip/hip_fp16.h>

#define TT 256
#define DD 128
#define NEG -30000.0f

typedef __attribute__((ext_vector_type(4))) float f32x4;
typedef __attribute__((ext_vector_type(8))) _Float16 f16x8;
typedef unsigned int u32;
typedef __attribute__((ext_vector_type(4))) u32 u32x4;
typedef unsigned short u16;

__device__ __forceinline__ u16 tof16(float v) {
  return __builtin_bit_cast(u16, (_Float16)v);
}
__device__ __forceinline__ u32 pkf16(float lo, float hi) {
  return (u32)tof16(lo) | ((u32)tof16(hi) << 16);
}
__device__ __forceinline__ f32x4 mfma16(f16x8 a, f16x8 b, f32x4 c) {
  return __builtin_amdgcn_mfma_f32_16x16x32_f16(a, b, c, 0, 0, 0);
}

// D-layout -> operand-frag repack (verified rounds 2-12).
template<int P>
__device__ __forceinline__ void convN(const f32x4* src, u32x4* dst, int l15, int g) {
  #pragma unroll
  for (int p = 0; p < P; ++p) {
    u32 p00 = pkf16(src[2*p][0], src[2*p][1]);
    u32 p01 = pkf16(src[2*p][2], src[2*p][3]);
    u32 p10 = pkf16(src[2*p+1][0], src[2*p+1][1]);
    u32 p11 = pkf16(src[2*p+1][2], src[2*p+1][3]);
    u32x4 w;
    #pragma unroll
    for (int wd = 0; wd < 4; ++wd) {
      int srcl = l15 + 16*((2*g + (wd >> 1)) & 3);
      u32 lo = (u32)__shfl((int)((wd & 1) ? p01 : p00), srcl, 64);
      u32 hi = (u32)__shfl((int)((wd & 1) ? p11 : p10), srcl, 64);
      w[wd] = (g >> 1) ? hi : lo;
    }
    dst[p] = w;
  }
}

// ---------------- precompute (verified round 2)
__global__ void precompute_k(const float* __restrict__ Wk, const float* __restrict__ Wq,
                             const float* __restrict__ bq, const float* __restrict__ Wv,
                             u16* __restrict__ MT, u16* __restrict__ WvB, float* __restrict__ m0) {
  int dp = blockIdx.x;
  int d  = threadIdx.x;
  float acc = 0.f;
  for (int e = 0; e < DD; ++e) acc = fmaf(Wq[e*DD + d], Wk[e*DD + dp], acc);
  MT[dp*DD + d] = tof16(acc);
  WvB[dp*DD + d] = tof16(Wv[dp*DD + d]);
  if (dp == 0) {
    float a0 = 0.f;
    for (int e = 0; e < DD; ++e) a0 = fmaf(bq[e], Wk[e*DD + d], a0);
    m0[d] = a0;
  }
}

// ---------------- per-q-tile pipeline (r11's verified body; vt now a GLOBAL
// pointer read through local-XCD L2 — r7's verified read pattern).
__device__ __forceinline__ void run_tile(int qt, const char* __restrict__ xhb,
                                         const char* __restrict__ vtb,
                                         const u16* __restrict__ MTg,
                                         const float* __restrict__ m0g,
                                         const float* __restrict__ bvg,
                                         float* __restrict__ outb,
                                         const int (&xoff)[4], int voff,
                                         int l15, int g) {
  // Phase A: A'[q][d'] strip -> B-frags bAw (verified)
  u32x4 bAw[4];
  {
    f16x8 bXq[4];
    #pragma unroll
    for (int kc = 0; kc < 4; ++kc)
      bXq[kc] = *(const f16x8*)(xhb + qt*4096 + xoff[kc]);
    f32x4 Aacc[8];
    #pragma unroll
    for (int dt = 0; dt < 8; ++dt) {
      f32x4 acc = {0.f, 0.f, 0.f, 0.f};
      #pragma unroll
      for (int kc = 0; kc < 4; ++kc) {
        f16x8 aM = *(const f16x8*)(MTg + (dt*16 + l15)*DD + kc*32 + g*8);
        acc = mfma16(aM, bXq[kc], acc);
      }
      f32x4 m0v = *(const f32x4*)(m0g + dt*16 + g*4);
      #pragma unroll
      for (int j = 0; j < 4; ++j) acc[j] += m0v[j];
      Aacc[dt] = acc;
    }
    convN<4>(Aacc, bAw, l15, g);
  }

  // Online chunk loop (verified r7-r11)
  const int nch = (qt + 2) >> 1;
  f32x4 oacc[8];
  #pragma unroll
  for (int et = 0; et < 8; ++et) { f32x4 z = {0.f,0.f,0.f,0.f}; oacc[et] = z; }
  float m = NEG, sum = 0.f;

  #pragma unroll 1
  for (int c = 0; c < nch; ++c) {
    const int kt0 = 2*c, kt1 = 2*c + 1;
    f32x4 s0 = {0.f, 0.f, 0.f, 0.f};
    f32x4 s1 = {NEG, NEG, NEG, NEG};
    #pragma unroll
    for (int kc = 0; kc < 4; ++kc) {
      f16x8 aX = *(const f16x8*)(xhb + kt0*4096 + xoff[kc]);
      s0 = mfma16(aX, __builtin_bit_cast(f16x8, bAw[kc]), s0);
    }
    if (kt0 == qt) {
      #pragma unroll
      for (int j = 0; j < 4; ++j)
        if (g*4 + j > l15) s0[j] = NEG;
    }
    if (kt1 <= qt) {
      f32x4 acc = {0.f, 0.f, 0.f, 0.f};
      #pragma unroll
      for (int kc = 0; kc < 4; ++kc) {
        f16x8 aX = *(const f16x8*)(xhb + kt1*4096 + xoff[kc]);
        acc = mfma16(aX, __builtin_bit_cast(f16x8, bAw[kc]), acc);
      }
      if (kt1 == qt) {
        #pragma unroll
        for (int j = 0; j < 4; ++j)
          if (g*4 + j > l15) acc[j] = NEG;
      }
      s1 = acc;
    }
    float pmax = NEG;
    #pragma unroll
    for (int j = 0; j < 4; ++j) pmax = fmaxf(pmax, fmaxf(s0[j], s1[j]));
    pmax = fmaxf(pmax, __shfl_xor(pmax, 16));
    pmax = fmaxf(pmax, __shfl_xor(pmax, 32));
    if (!__all(pmax <= m + 8.f)) {
      float mn = fmaxf(m, pmax);
      float f  = __expf(m - mn);        // 0 on first chunk (m=NEG)
      sum *= f;
      #pragma unroll
      for (int et = 0; et < 8; ++et) {
        #pragma unroll
        for (int j = 0; j < 4; ++j) oacc[et][j] *= f;
      }
      m = mn;
    }
    #pragma unroll
    for (int j = 0; j < 4; ++j) {
      float p0 = __expf(s0[j] - m); s0[j] = p0; sum += p0;
      float p1 = __expf(s1[j] - m); s1[j] = p1; sum += p1;   // 0 if kt1 invalid
    }
    u32 p00 = pkf16(s0[0], s0[1]);
    u32 p01 = pkf16(s0[2], s0[3]);
    u32 p10 = pkf16(s1[0], s1[1]);
    u32 p11 = pkf16(s1[2], s1[3]);
    u32x4 pw;
    #pragma unroll
    for (int wd = 0; wd < 4; ++wd) {
      int srcl = l15 + 16*((2*g + (wd >> 1)) & 3);
      u32 lo = (u32)__shfl((int)((wd & 1) ? p01 : p00), srcl, 64);
      u32 hi = (u32)__shfl((int)((wd & 1) ? p11 : p10), srcl, 64);
      pw[wd] = (g >> 1) ? hi : lo;
    }
    f16x8 pb = __builtin_bit_cast(f16x8, pw);
    #pragma unroll
    for (int et = 0; et < 8; ++et) {
      f16x8 aV = *(const f16x8*)(vtb + et*8192 + c*1024 + voff);
      oacc[et] = mfma16(aV, pb, oacc[et]);
    }
  }

  // Epilogue: normalize + bv; store (verified layout)
  sum += __shfl_xor(sum, 16);
  sum += __shfl_xor(sum, 32);
  const float inv = 1.f / sum;
  #pragma unroll
  for (int et = 0; et < 8; ++et) {
    f32x4 bvv = *(const f32x4*)(bvg + et*16 + g*4);
    f32x4 o;
    #pragma unroll
    for (int j = 0; j < 4; ++j) o[j] = oacc[et][j]*inv + bvv[j];
    *(f32x4*)(outb + (qt*16 + l15)*DD + et*16 + g*4) = o;
  }
}

// ---------------- fused head: 1 block = 1 batch, 8 waves (512 thr), 64 KB LDS
// (xh only -> 2 blocks/CU, 4 waves/SIMD). vt frags go to workspace and are
// read back through the local XCD's L2 (this block is the only reader; the
// vmcnt(0) drain in __syncthreads makes the writes visible).
__global__ __launch_bounds__(512, 4)
void head_fused(const float* __restrict__ x, const u16* __restrict__ MTg,
                const u16* __restrict__ WvB, const float* __restrict__ m0g,
                const float* __restrict__ bvg, char* __restrict__ vtg,
                float* __restrict__ out) {
  extern __shared__ char lds[];
  char* xhb = lds;            // xh frags (64 KB, swizzled: l15s = l15 ^ (kc*4+g))

  const int tid  = threadIdx.x;
  const int w    = tid >> 6;
  const int lane = tid & 63;
  const int l15  = lane & 15;
  const int g    = lane >> 4;
  const int b    = blockIdx.x;
  const float* xb = x + (size_t)b * (TT*DD);
  char* vtb = vtg + (size_t)b * 65536;

  int xoff[4];
  #pragma unroll
  for (int kc = 0; kc < 4; ++kc)
    xoff[kc] = kc*1024 + g*256 + (l15 ^ (kc*4 + g))*16;
  const int voff = g*256 + l15*16;

  // ---- Stage: x f32 -> f16 frags in LDS (verified r9/r11)
  #pragma unroll
  for (int i = 0; i < 8; ++i) {
    int slot = tid + i*512;
    int row = slot >> 4, cg = slot & 15;
    const float* p = xb + row*DD + cg*8;
    f32x4 v0 = *(const f32x4*)p, v1 = *(const f32x4*)(p + 4);
    u32x4 pk;
    pk[0] = pkf16(v0[0], v0[1]); pk[1] = pkf16(v0[2], v0[3]);
    pk[2] = pkf16(v1[0], v1[1]); pk[3] = pkf16(v1[2], v1[3]);
    *(u32x4*)(xhb + (row >> 4)*4096 + (cg >> 2)*1024 + (cg & 3)*256
                  + ((row & 15) ^ cg)*16) = pk;
  }
  __syncthreads();

  // ---- VT: wave w builds vt chunk c=w, all 8 et (verified r8-r11 math);
  // frags stored to ws (coalesced dwordx4, r7's verified layout).
  {
    const int c = w;
    f16x8 bX[2][4];
    #pragma unroll
    for (int t = 0; t < 2; ++t)
      #pragma unroll
      for (int kc = 0; kc < 4; ++kc)
        bX[t][kc] = *(const f16x8*)(xhb + (2*c + t)*4096 + xoff[kc]);
    #pragma unroll
    for (int et = 0; et < 8; ++et) {
      f16x8 bWv[4];
      #pragma unroll
      for (int kc = 0; kc < 4; ++kc)
        bWv[kc] = *(const f16x8*)(WvB + (et*16 + l15)*DD + kc*32 + g*8);
      f32x4 vacc[2];
      #pragma unroll
      for (int t = 0; t < 2; ++t) {
        f32x4 acc = {0.f, 0.f, 0.f, 0.f};
        #pragma unroll
        for (int kc = 0; kc < 4; ++kc) acc = mfma16(bX[t][kc], bWv[kc], acc);
        vacc[t] = acc;
      }
      u32x4 dv[1];
      convN<1>(vacc, dv, l15, g);
      *(u32x4*)(vtb + et*8192 + c*1024 + voff) = dv[0];
    }
  }
  __syncthreads();   // vmcnt(0)+barrier: vt stores visible to all waves via L2

  // ---- Two balanced q-tiles per wave, sequential (9 chunks total per wave)
  float* outb = out + (size_t)b * (TT*DD);
  run_tile(15 - w, xhb, vtb, MTg, m0g, bvg, outb, xoff, voff, l15, g);
  run_tile(w,      xhb, vtb, MTg, m0g, bvg, outb, xoff, voff, l15, g);
}

// ================= launcher =================
extern "C" void kernel_launch(void* const* d_in, const int* in_sizes, int n_in,
                              void* d_out, int out_size, void* d_ws, size_t ws_size,
                              hipStream_t stream) {
  (void)in_sizes; (void)n_in; (void)out_size; (void)ws_size;
  const float* x  = (const float*)d_in[0];
  const float* Wk = (const float*)d_in[1];
  // d_in[2] = bk: only per-q-row constants in scores -> dropped by softmax
  const float* Wq = (const float*)d_in[3];
  const float* bq = (const float*)d_in[4];
  const float* Wv = (const float*)d_in[5];
  const float* bv = (const float*)d_in[6];

  char* ws = (char*)d_ws;
  u16*   MT  = (u16*)ws;               // 32 KB
  u16*   WvB = (u16*)(ws + 32768);     // 32 KB
  float* m0  = (float*)(ws + 65536);   // 512 B
  char*  vtg = ws + (1 << 20);         // 33.5 MB of vt frags (512 x 64 KB)

  (void)hipFuncSetAttribute((const void*)head_fused,
                            hipFuncAttributeMaxDynamicSharedMemorySize, 65536);

  precompute_k<<<128, 128, 0, stream>>>(Wk, Wq, bq, Wv, MT, WvB, m0);
  head_fused<<<512, 512, 65536, stream>>>(x, MT, WvB, m0, bv, vtg, (float*)d_out);
}

// Round 16
// 86.896 us; speedup vs baseline: 4.1143x; 1.4632x over previous
//
#include <hip/hip_runtime.h>
#include <hip/hip_fp16.h>

#define TT 256
#define DD 128
#define NEG -30000.0f
#define LOG2E 1.44269504088896340736f

typedef __attribute__((ext_vector_type(4))) float f32x4;
typedef __attribute__((ext_vector_type(8))) _Float16 f16x8;
typedef unsigned int u32;
typedef __attribute__((ext_vector_type(4))) u32 u32x4;
typedef unsigned short u16;

__device__ __forceinline__ u16 tof16(float v) {
  return __builtin_bit_cast(u16, (_Float16)v);
}
__device__ __forceinline__ u32 pkf16(float lo, float hi) {
  return (u32)tof16(lo) | ((u32)tof16(hi) << 16);
}
__device__ __forceinline__ f32x4 mfma16(f16x8 a, f16x8 b, f32x4 c) {
  return __builtin_amdgcn_mfma_f32_16x16x32_f16(a, b, c, 0, 0, 0);
}

// D-layout -> operand-frag repack (verified rounds 2-15).
template<int P>
__device__ __forceinline__ void convN(const f32x4* src, u32x4* dst, int l15, int g) {
  #pragma unroll
  for (int p = 0; p < P; ++p) {
    u32 p00 = pkf16(src[2*p][0], src[2*p][1]);
    u32 p01 = pkf16(src[2*p][2], src[2*p][3]);
    u32 p10 = pkf16(src[2*p+1][0], src[2*p+1][1]);
    u32 p11 = pkf16(src[2*p+1][2], src[2*p+1][3]);
    u32x4 w;
    #pragma unroll
    for (int wd = 0; wd < 4; ++wd) {
      int srcl = l15 + 16*((2*g + (wd >> 1)) & 3);
      u32 lo = (u32)__shfl((int)((wd & 1) ? p01 : p00), srcl, 64);
      u32 hi = (u32)__shfl((int)((wd & 1) ? p11 : p10), srcl, 64);
      w[wd] = (g >> 1) ? hi : lo;
    }
    dst[p] = w;
  }
}

// ---------------- precompute (verified round 2); MT and m0 PRE-SCALED by
// log2(e) so the softmax runs in the exp2 domain (saves a mul per element).
__global__ void precompute_k(const float* __restrict__ Wk, const float* __restrict__ Wq,
                             const float* __restrict__ bq, const float* __restrict__ Wv,
                             u16* __restrict__ MT, u16* __restrict__ WvB, float* __restrict__ m0) {
  int dp = blockIdx.x;
  int d  = threadIdx.x;
  float acc = 0.f;
  for (int e = 0; e < DD; ++e) acc = fmaf(Wq[e*DD + d], Wk[e*DD + dp], acc);
  MT[dp*DD + d] = tof16(acc * LOG2E);
  WvB[dp*DD + d] = tof16(Wv[dp*DD + d]);
  if (dp == 0) {
    float a0 = 0.f;
    for (int e = 0; e < DD; ++e) a0 = fmaf(bq[e], Wk[e*DD + d], a0);
    m0[d] = a0 * LOG2E;
  }
}

// ---------------- per-q-tile pipeline: phaseA -> 4-ktile online chunks -> store.
// 4-ktile chunks halve the pmax-shfl rounds and rescale branches per element;
// chunk count per wave-pair is exactly 5 for every wave (balance preserved).
__device__ __forceinline__ void run_tile(int qt, const char* __restrict__ xhb,
                                         const char* __restrict__ vtb,
                                         const u16* __restrict__ MTg,
                                         const float* __restrict__ m0g,
                                         const float* __restrict__ bvg,
                                         float* __restrict__ outb,
                                         const int (&xoff)[4], int voff,
                                         int l15, int g) {
  // Phase A: A'[q][d'] strip -> B-frags bAw (verified; now in log2 domain)
  u32x4 bAw[4];
  {
    f16x8 bXq[4];
    #pragma unroll
    for (int kc = 0; kc < 4; ++kc)
      bXq[kc] = *(const f16x8*)(xhb + qt*4096 + xoff[kc]);
    f32x4 Aacc[8];
    #pragma unroll
    for (int dt = 0; dt < 8; ++dt) {
      f32x4 acc = {0.f, 0.f, 0.f, 0.f};
      #pragma unroll
      for (int kc = 0; kc < 4; ++kc) {
        f16x8 aM = *(const f16x8*)(MTg + (dt*16 + l15)*DD + kc*32 + g*8);
        acc = mfma16(aM, bXq[kc], acc);
      }
      f32x4 m0v = *(const f32x4*)(m0g + dt*16 + g*4);
      #pragma unroll
      for (int j = 0; j < 4; ++j) acc[j] += m0v[j];
      Aacc[dt] = acc;
    }
    convN<4>(Aacc, bAw, l15, g);
  }

  // Online 4-ktile chunk loop
  const int nch4 = (qt + 4) >> 2;
  f32x4 oacc[8];
  #pragma unroll
  for (int et = 0; et < 8; ++et) { f32x4 z = {0.f,0.f,0.f,0.f}; oacc[et] = z; }
  float m = NEG, sum = 0.f;

  #pragma unroll 1
  for (int c4 = 0; c4 < nch4; ++c4) {
    f32x4 s[4];
    #pragma unroll
    for (int t = 0; t < 4; ++t) { f32x4 z = {NEG, NEG, NEG, NEG}; s[t] = z; }
    #pragma unroll
    for (int t = 0; t < 4; ++t) {
      const int kt = 4*c4 + t;
      if (kt <= qt) {                  // wave-uniform
        f32x4 acc = {0.f, 0.f, 0.f, 0.f};
        #pragma unroll
        for (int kc = 0; kc < 4; ++kc) {
          f16x8 aX = *(const f16x8*)(xhb + kt*4096 + xoff[kc]);
          acc = mfma16(aX, __builtin_bit_cast(f16x8, bAw[kc]), acc);
        }
        if (kt == qt) {                // diagonal: keep k_local <= q_local
          #pragma unroll
          for (int j = 0; j < 4; ++j)
            if (g*4 + j > l15) acc[j] = NEG;
        }
        s[t] = acc;
      }
    }
    // one pmax reduction + one rescale decision per 4 k-tiles
    float pmax = NEG;
    #pragma unroll
    for (int t = 0; t < 4; ++t) {
      #pragma unroll
      for (int j = 0; j < 4; ++j) pmax = fmaxf(pmax, s[t][j]);
    }
    pmax = fmaxf(pmax, __shfl_xor(pmax, 16));
    pmax = fmaxf(pmax, __shfl_xor(pmax, 32));
    if (!__all(pmax <= m + 11.5416f)) {   // 8 * log2(e)
      float mn = fmaxf(m, pmax);
      float f  = exp2f(m - mn);           // 0 on first chunk (m=NEG)
      sum *= f;
      #pragma unroll
      for (int et = 0; et < 8; ++et) {
        #pragma unroll
        for (int j = 0; j < 4; ++j) oacc[et][j] *= f;
      }
      m = mn;
    }
    #pragma unroll
    for (int t = 0; t < 4; ++t) {
      #pragma unroll
      for (int j = 0; j < 4; ++j) {
        float p = exp2f(s[t][j] - m);     // invalid tiles: exp2(-big) = 0
        s[t][j] = p;
        sum += p;
      }
    }
    // two pf+PV halves (vt chunk index 2*c4+h)
    #pragma unroll
    for (int h = 0; h < 2; ++h) {
      if (4*c4 + 2*h <= qt) {             // wave-uniform
        u32 p00 = pkf16(s[2*h][0], s[2*h][1]);
        u32 p01 = pkf16(s[2*h][2], s[2*h][3]);
        u32 p10 = pkf16(s[2*h+1][0], s[2*h+1][1]);
        u32 p11 = pkf16(s[2*h+1][2], s[2*h+1][3]);
        u32x4 pw;
        #pragma unroll
        for (int wd = 0; wd < 4; ++wd) {
          int srcl = l15 + 16*((2*g + (wd >> 1)) & 3);
          u32 lo = (u32)__shfl((int)((wd & 1) ? p01 : p00), srcl, 64);
          u32 hi = (u32)__shfl((int)((wd & 1) ? p11 : p10), srcl, 64);
          pw[wd] = (g >> 1) ? hi : lo;
        }
        f16x8 pb = __builtin_bit_cast(f16x8, pw);
        #pragma unroll
        for (int et = 0; et < 8; ++et) {
          f16x8 aV = *(const f16x8*)(vtb + et*8192 + (2*c4 + h)*1024 + voff);
          oacc[et] = mfma16(aV, pb, oacc[et]);
        }
      }
    }
  }

  // Epilogue: normalize + bv; store (verified layout)
  sum += __shfl_xor(sum, 16);
  sum += __shfl_xor(sum, 32);
  const float inv = 1.f / sum;
  #pragma unroll
  for (int et = 0; et < 8; ++et) {
    f32x4 bvv = *(const f32x4*)(bvg + et*16 + g*4);
    f32x4 o;
    #pragma unroll
    for (int j = 0; j < 4; ++j) o[j] = oacc[et][j]*inv + bvv[j];
    *(f32x4*)(outb + (qt*16 + l15)*DD + et*16 + g*4) = o;
  }
}

// ---------------- fused head: 1 block = 1 batch, 8 waves (512 thr), 128 KB LDS.
// Wave w handles q-tiles {15-w, w} sequentially (5 chunk4's total, balanced).
__global__ __launch_bounds__(512, 2)
void head_fused(const float* __restrict__ x, const u16* __restrict__ MTg,
                const u16* __restrict__ WvB, const float* __restrict__ m0g,
                const float* __restrict__ bvg, float* __restrict__ out) {
  extern __shared__ char lds[];
  char* xhb = lds;            // xh frags (64 KB, swizzled: l15s = l15 ^ (kc*4+g))
  char* vtb = lds + 65536;    // vt frags (64 KB, linear)

  const int tid  = threadIdx.x;
  const int w    = tid >> 6;
  const int lane = tid & 63;
  const int l15  = lane & 15;
  const int g    = lane >> 4;
  const int b    = blockIdx.x;
  const float* xb = x + (size_t)b * (TT*DD);

  int xoff[4];
  #pragma unroll
  for (int kc = 0; kc < 4; ++kc)
    xoff[kc] = kc*1024 + g*256 + (l15 ^ (kc*4 + g))*16;
  const int voff = g*256 + l15*16;

  // ---- Stage: x f32 -> f16 frags in LDS (verified r9/r11)
  #pragma unroll
  for (int i = 0; i < 8; ++i) {
    int slot = tid + i*512;
    int row = slot >> 4, cg = slot & 15;
    const float* p = xb + row*DD + cg*8;
    f32x4 v0 = *(const f32x4*)p, v1 = *(const f32x4*)(p + 4);
    u32x4 pk;
    pk[0] = pkf16(v0[0], v0[1]); pk[1] = pkf16(v0[2], v0[3]);
    pk[2] = pkf16(v1[0], v1[1]); pk[3] = pkf16(v1[2], v1[3]);
    *(u32x4*)(xhb + (row >> 4)*4096 + (cg >> 2)*1024 + (cg & 3)*256
                  + ((row & 15) ^ cg)*16) = pk;
  }
  __syncthreads();

  // ---- VT: wave w builds vt chunk c=w, all 8 et (verified r8-r11 math)
  {
    const int c = w;
    f16x8 bX[2][4];
    #pragma unroll
    for (int t = 0; t < 2; ++t)
      #pragma unroll
      for (int kc = 0; kc < 4; ++kc)
        bX[t][kc] = *(const f16x8*)(xhb + (2*c + t)*4096 + xoff[kc]);
    #pragma unroll
    for (int et = 0; et < 8; ++et) {
      f16x8 bWv[4];
      #pragma unroll
      for (int kc = 0; kc < 4; ++kc)
        bWv[kc] = *(const f16x8*)(WvB + (et*16 + l15)*DD + kc*32 + g*8);
      f32x4 vacc[2];
      #pragma unroll
      for (int t = 0; t < 2; ++t) {
        f32x4 acc = {0.f, 0.f, 0.f, 0.f};
        #pragma unroll
        for (int kc = 0; kc < 4; ++kc) acc = mfma16(bX[t][kc], bWv[kc], acc);
        vacc[t] = acc;
      }
      u32x4 dv[1];
      convN<1>(vacc, dv, l15, g);
      *(u32x4*)(vtb + et*8192 + c*1024 + voff) = dv[0];
    }
  }
  __syncthreads();

  // ---- Two balanced q-tiles per wave, sequential
  float* outb = out + (size_t)b * (TT*DD);
  run_tile(15 - w, xhb, vtb, MTg, m0g, bvg, outb, xoff, voff, l15, g);
  run_tile(w,      xhb, vtb, MTg, m0g, bvg, outb, xoff, voff, l15, g);
}

// ================= launcher =================
extern "C" void kernel_launch(void* const* d_in, const int* in_sizes, int n_in,
                              void* d_out, int out_size, void* d_ws, size_t ws_size,
                              hipStream_t stream) {
  (void)in_sizes; (void)n_in; (void)out_size; (void)ws_size;
  const float* x  = (const float*)d_in[0];
  const float* Wk = (const float*)d_in[1];
  // d_in[2] = bk: only per-q-row constants in scores -> dropped by softmax
  const float* Wq = (const float*)d_in[3];
  const float* bq = (const float*)d_in[4];
  const float* Wv = (const float*)d_in[5];
  const float* bv = (const float*)d_in[6];

  char* ws = (char*)d_ws;
  u16*   MT  = (u16*)ws;               // 32 KB
  u16*   WvB = (u16*)(ws + 32768);     // 32 KB
  float* m0  = (float*)(ws + 65536);   // 512 B

  (void)hipFuncSetAttribute((const void*)head_fused,
                            hipFuncAttributeMaxDynamicSharedMemorySize, 131072);

  precompute_k<<<128, 128, 0, stream>>>(Wk, Wq, bq, Wv, MT, WvB, m0);
  head_fused<<<512, 512, 131072, stream>>>(x, MT, WvB, m0, bv, (float*)d_out);
}